// Round 14
// baseline (298.508 us; speedup 1.0000x reference)
//
#include <hip/hip_runtime.h>

// Problem: nearest = memory[argmax_m cosine(x_row, memory_m)], plus copy of x.
//   x: 65536 x 1024 f32, memory: 40 x 1024 f32, out = [nearest | x-copy]
//
// R14: STREAM UNMIXING. R9/R13's fused loop mixed {HBM reads, strided nt HBM
// writes, L2 B-reads} and ran at ~2.5 TB/s while the harness's pure-write
// fill does 6.7 TB/s on the same buffers. Split:
//   K2a (k_main): R9's MFMA sims kernel WITHOUT the per-step x-copy stores
//        (pure read + end gather burst), 2-deep named A-prefetch, B-first.
//   K2b (k_copy): grid-stride float4 x -> out_x copy (the 6.3 TB/s pattern).
// Argmax/flag/f64-refine net byte-identical to validated R9 (absmax=0).
//
// d_ws layout (bytes):
//   [0,      320) : double inv64[40]
//   [320,    480) : float  inv32[40]
//   [512,  16896) : uint flagbits[4096]  (16-bit mask per 16-row wave)
//   [32768,131072): ushort bhi[48][1024] (bf16 hi of mem*inv32, rows 40-47 = 0)
//   [131072,229376): ushort blo[48][1024] (bf16 lo)

#define DIM 1024
#define NMEM 40

typedef float  vf4 __attribute__((ext_vector_type(4)));
typedef float  f4a __attribute__((ext_vector_type(4)));
typedef short  s8v __attribute__((ext_vector_type(8)));

union FragU { s8v v; unsigned int u[4]; };

constexpr float TAU = 2.5e-4f;   // normalized top-2 gap below which f64 re-resolve

// ---------------- Kernel 1: memory-row inverse norms (f32 + f64) ----------------
__global__ __launch_bounds__(64) void k_norms(const float* __restrict__ mem,
                                              double* __restrict__ inv64,
                                              float* __restrict__ inv32) {
  const int m = blockIdx.x;      // 40 blocks, 1 wave each
  const int lane = threadIdx.x;
  const float* __restrict__ row = mem + (size_t)m * DIM;
  double s = 0.0;
#pragma unroll
  for (int i = 0; i < DIM / 64; ++i) {
    double v = (double)row[lane + 64 * i];
    s = fma(v, v, s);
  }
#pragma unroll
  for (int off = 32; off > 0; off >>= 1) s += __shfl_xor(s, off, 64);
  if (lane == 0) {
    double n = sqrt(s);
    n = (n > 1e-8) ? n : 1e-8;
    inv64[m] = 1.0 / n;
    inv32[m] = (float)(1.0 / n);
  }
}

// ---------------- Kernel 1b: split normalized memory into bf16 hi/lo ----------------
__global__ __launch_bounds__(256) void k_prep(const float* __restrict__ mem,
                                              const float* __restrict__ inv32,
                                              unsigned short* __restrict__ bhi,
                                              unsigned short* __restrict__ blo) {
  const int m = blockIdx.x;            // 0..47 (40 real + 8 zero-pad)
  const int k0 = threadIdx.x * 4;      // 1024/256 = 4 elems/thread
  if (m < NMEM) {
    const float s = inv32[m];
#pragma unroll
    for (int j = 0; j < 4; ++j) {
      float w = mem[(size_t)m * DIM + k0 + j] * s;
      unsigned int u = __builtin_bit_cast(unsigned int, w);
      bhi[(size_t)m * DIM + k0 + j] = (unsigned short)(u >> 16);
      float hf = __builtin_bit_cast(float, u & 0xFFFF0000u);
      float lo = w - hf;
      blo[(size_t)m * DIM + k0 + j] =
          (unsigned short)(__builtin_bit_cast(unsigned int, lo) >> 16);
    }
  } else {
#pragma unroll
    for (int j = 0; j < 4; ++j) {
      bhi[(size_t)m * DIM + k0 + j] = 0;
      blo[(size_t)m * DIM + k0 + j] = 0;
    }
  }
}

// ---------------- Kernel 2a: MFMA sims + argmax + gather (NO x-copy) ----------------
// Block = 256 thr = 4 independent waves (no barriers). Wave = 16 x-rows.
// A-frag (x): lane holds row (l&15), k-slice (l>>4)*8..+8 -> coalesced 128B
// lines. B-frag (mem): lane holds m-col (l&15)+16*tile, same k-slice.
// C layout (m89-verified): lane holds D[(l>>4)*4+j][(l&15)+16*tile].
// Per step, issue order: B(t) loads -> A(t+2) refill. No stores in the loop.
__global__ __launch_bounds__(256, 4) void k_main(const float* __restrict__ x,
                                                 const float* __restrict__ mem,
                                                 const unsigned short* __restrict__ bhi,
                                                 const unsigned short* __restrict__ blo,
                                                 float* __restrict__ out_near,
                                                 unsigned int* __restrict__ flagbits) {
  __shared__ float nxw[4][16];
  __shared__ int   amaxw[4][16];
  __shared__ int   flagw[4][16];

  const int tid  = threadIdx.x;
  const int lane = tid & 63;
  const int w    = __builtin_amdgcn_readfirstlane(tid >> 6);
  const int row  = lane & 15;          // x-row within wave tile / m-col within tile
  const int kg   = lane >> 4;          // k-subslice group (0..3)
  const int rowbase = blockIdx.x * 64 + w * 16;

  const float* __restrict__ xp  = x + (size_t)(rowbase + row) * DIM + kg * 8;
  const unsigned short* __restrict__ bp = bhi + (size_t)row * DIM + kg * 8;
  const unsigned short* __restrict__ lp = blo + (size_t)row * DIM + kg * 8;

  f4a acc[3];
#pragma unroll
  for (int t = 0; t < 3; ++t) acc[t] = (f4a){0.f, 0.f, 0.f, 0.f};
  float nx = 0.f;

  // 2-deep A prefetch, NAMED slots (no runtime indexing -> no scratch)
  vf4 S0a, S0b, S1a, S1b;
  S0a = *(const vf4*)(xp + 0 * 32);  S0b = *(const vf4*)(xp + 0 * 32 + 4);
  S1a = *(const vf4*)(xp + 1 * 32);  S1b = *(const vf4*)(xp + 1 * 32 + 4);

#define STEP(T, Sa, Sb, PF)                                                     \
  {                                                                             \
    s8v bh[3], bl[3];                                                           \
    _Pragma("unroll")                                                           \
    for (int tt = 0; tt < 3; ++tt) {                                            \
      bh[tt] = *(const s8v*)(bp + (size_t)tt * 16 * DIM + (T) * 32);            \
      bl[tt] = *(const s8v*)(lp + (size_t)tt * 16 * DIM + (T) * 32);            \
    }                                                                           \
    vf4 a0 = Sa, a1 = Sb;                                                       \
    if (PF) {                                                                   \
      Sa = *(const vf4*)(xp + ((T) + 2) * 32);                                  \
      Sb = *(const vf4*)(xp + ((T) + 2) * 32 + 4);                              \
    }                                                                           \
    nx = fmaf(a0.x, a0.x, fmaf(a0.y, a0.y, fmaf(a0.z, a0.z, fmaf(a0.w, a0.w, nx)))); \
    nx = fmaf(a1.x, a1.x, fmaf(a1.y, a1.y, fmaf(a1.z, a1.z, fmaf(a1.w, a1.w, nx)))); \
    FragU ah, al;                                                               \
    {                                                                           \
      float f[8] = {a0.x, a0.y, a0.z, a0.w, a1.x, a1.y, a1.z, a1.w};            \
      _Pragma("unroll")                                                         \
      for (int p = 0; p < 4; ++p) {                                             \
        unsigned int u0 = __builtin_bit_cast(unsigned int, f[2 * p]);           \
        unsigned int u1 = __builtin_bit_cast(unsigned int, f[2 * p + 1]);       \
        ah.u[p] = (u1 & 0xFFFF0000u) | (u0 >> 16);                              \
        float h0 = __builtin_bit_cast(float, u0 & 0xFFFF0000u);                 \
        float h1 = __builtin_bit_cast(float, u1 & 0xFFFF0000u);                 \
        float l0 = f[2 * p] - h0;                                               \
        float l1 = f[2 * p + 1] - h1;                                           \
        al.u[p] = (__builtin_bit_cast(unsigned int, l1) & 0xFFFF0000u) |        \
                  (__builtin_bit_cast(unsigned int, l0) >> 16);                 \
      }                                                                         \
    }                                                                           \
    _Pragma("unroll")                                                           \
    for (int tt = 0; tt < 3; ++tt) {                                            \
      acc[tt] = __builtin_amdgcn_mfma_f32_16x16x32_bf16(ah.v, bh[tt], acc[tt], 0, 0, 0); \
      acc[tt] = __builtin_amdgcn_mfma_f32_16x16x32_bf16(ah.v, bl[tt], acc[tt], 0, 0, 0); \
      acc[tt] = __builtin_amdgcn_mfma_f32_16x16x32_bf16(al.v, bh[tt], acc[tt], 0, 0, 0); \
      acc[tt] = __builtin_amdgcn_mfma_f32_16x16x32_bf16(al.v, bl[tt], acc[tt], 0, 0, 0); \
    }                                                                           \
  }

#pragma unroll 1
  for (int t = 0; t < 28; t += 2) {    // steady state: refills t+2, t+3
    STEP(t + 0, S0a, S0b, true)
    STEP(t + 1, S1a, S1b, true)
  }
  STEP(28, S0a, S0b, true)             // loads 30
  STEP(29, S1a, S1b, true)             // loads 31
  STEP(30, S0a, S0b, false)
  STEP(31, S1a, S1b, false)
#undef STEP

  // ||x||^2: sum the 4 k-groups (lanes l, l^16, l^32, l^48 share row l&15)
  nx += __shfl_xor(nx, 16, 64);
  nx += __shfl_xor(nx, 32, 64);
  if (lane < 16) nxw[w][lane] = nx;

  // per-lane top-2: lane holds sims for rows (l>>4)*4+j, m-cols (l&15)+16t
  float v1[4], v2[4];
  int   i1[4];
#pragma unroll
  for (int j = 0; j < 4; ++j) {
    float c0 = acc[0][j], c1 = acc[1][j];
    float c2 = (row < 8) ? acc[2][j] : -3.4e38f;   // cols 40-47 are pad
    float a1 = c0, a2 = -3.4e38f;
    int   ai = row;
    if (c1 > a1) { a2 = a1; a1 = c1; ai = row + 16; } else a2 = c1;
    if (c2 > a1) { a2 = a1; a1 = c2; ai = row + 32; } else if (c2 > a2) a2 = c2;
    v1[j] = a1; v2[j] = a2; i1[j] = ai;
  }
#pragma unroll
  for (int st = 1; st < 16; st <<= 1) {  // reduce over the 16 lanes of each row-group
#pragma unroll
    for (int j = 0; j < 4; ++j) {
      float o1 = __shfl_xor(v1[j], st, 64);
      float o2 = __shfl_xor(v2[j], st, 64);
      int   oi = __shfl_xor(i1[j], st, 64);
      if (o1 > v1[j]) { v2[j] = fmaxf(v1[j], o2); v1[j] = o1; i1[j] = oi; }
      else            { v2[j] = fmaxf(v2[j], o1); }           // tie -> gap 0 -> flagged
    }
  }
  if ((lane & 15) == 0) {
    const int g = lane >> 4;
#pragma unroll
    for (int j = 0; j < 4; ++j) {
      const int r = 4 * g + j;
      float gap = (v1[j] - v2[j]) * rsqrtf(fmaxf(nxw[w][r], 1e-30f));
      flagw[w][r] = !(gap >= TAU);     // NaN-safe
      amaxw[w][r] = i1[j];
    }
  }
  int flv = flagw[w][lane & 15];
  unsigned long long bmask = __ballot(flv != 0);
  if (lane == 0) flagbits[blockIdx.x * 4 + w] = (unsigned int)(bmask & 0xFFFFull);

  // gather-copy memory[amax] -> out_near (16 rows/wave, coalesced; nt: 1KB
  // contiguous per instruction = full lines)
  const vf4* __restrict__ m4 = (const vf4*)mem;
#pragma unroll 1
  for (int r = 0; r < 16; ++r) {
    int am = __builtin_amdgcn_readfirstlane(amaxw[w][r]);
    const vf4* __restrict__ src = m4 + (size_t)am * (DIM / 4);
    vf4* __restrict__ dst = (vf4*)out_near + (size_t)(rowbase + r) * (DIM / 4);
#pragma unroll
    for (int j = 0; j < 4; ++j) {
      vf4 v = src[lane + 64 * j];
      __builtin_nontemporal_store(v, &dst[lane + 64 * j]);
    }
  }
}

// ---------------- Kernel 2b: pure x -> out_x copy (clean stream regime) ----------------
__global__ __launch_bounds__(256) void k_copy(const float* __restrict__ x,
                                              float* __restrict__ out_x,
                                              int n4) {
  const vf4* __restrict__ src = (const vf4*)x;
  vf4* __restrict__ dst = (vf4*)out_x;
  int idx = blockIdx.x * 256 + threadIdx.x;
  const int stride = gridDim.x * 256;
#pragma unroll 4
  for (int i = idx; i < n4; i += stride) {
    vf4 v = src[i];
    __builtin_nontemporal_store(v, &dst[i]);
  }
}

// ---------------- Kernel 3: f64 re-resolution of razor-thin rows ----------------
__global__ __launch_bounds__(256) void k_refine(const float* __restrict__ x,
                                                const float* __restrict__ mem,
                                                const double* __restrict__ inv64,
                                                const unsigned int* __restrict__ flagbits,
                                                float* __restrict__ out_near) {
  unsigned int mask = flagbits[blockIdx.x];
  if (mask == 0u) return;                   // uniform; nearly all blocks exit
  const int tid = threadIdx.x;
  const int lane = tid & 63;
  const int wid = tid >> 6;
  __shared__ double bval[4];
  __shared__ int bidx[4];
  while (mask) {
    int r = __ffs(mask) - 1;
    mask &= (mask - 1u);
    int rrow = blockIdx.x * 16 + r;
    const float* __restrict__ xr = x + (size_t)rrow * DIM;
    double xd[16];
#pragma unroll
    for (int i = 0; i < 16; ++i) xd[i] = (double)xr[lane + 64 * i];
    double best = -1e300;
    int bi = 0;
    for (int q = 0; q < 10; ++q) {
      int m = wid * 10 + q;
      const float* __restrict__ mr = mem + (size_t)m * DIM;
      double s = 0.0;
#pragma unroll
      for (int i = 0; i < 16; ++i) s = fma(xd[i], (double)mr[lane + 64 * i], s);
#pragma unroll
      for (int off = 32; off > 0; off >>= 1) s += __shfl_xor(s, off, 64);
      double v = s * inv64[m];              // identical (bitwise) across lanes
      if (v > best) { best = v; bi = m; }   // strict > keeps lowest m on ties
    }
    if (lane == 0) { bval[wid] = best; bidx[wid] = bi; }
    __syncthreads();
    double g = bval[0];
    int gi = bidx[0];
#pragma unroll
    for (int gg = 1; gg < 4; ++gg) {
      if (bval[gg] > g) { g = bval[gg]; gi = bidx[gg]; }
    }
    const float4* __restrict__ src = (const float4*)mem + (size_t)gi * (DIM / 4);
    float4* __restrict__ dst = (float4*)out_near + (size_t)rrow * (DIM / 4);
    dst[tid] = src[tid];                    // 256 x 16B = full row, coalesced
    __syncthreads();                        // LDS reuse guard for next flagged row
  }
}

extern "C" void kernel_launch(void* const* d_in, const int* in_sizes, int n_in,
                              void* d_out, int out_size, void* d_ws, size_t ws_size,
                              hipStream_t stream) {
  const float* x   = (const float*)d_in[0];
  const float* mem = (const float*)d_in[1];
  // d_in[2] = top_k (unused: reference only consumes idx[:,0], i.e. the argmax)

  const int n_rows = in_sizes[0] / DIM;          // 65536
  float* out_near = (float*)d_out;
  float* out_x    = (float*)d_out + (size_t)n_rows * DIM;

  double* inv64 = (double*)d_ws;
  float*  inv32 = (float*)((char*)d_ws + 320);
  unsigned int* flagbits = (unsigned int*)((char*)d_ws + 512);
  unsigned short* bhi = (unsigned short*)((char*)d_ws + 32768);
  unsigned short* blo = (unsigned short*)((char*)d_ws + 131072);

  hipLaunchKernelGGL(k_norms, dim3(NMEM), dim3(64), 0, stream, mem, inv64, inv32);
  hipLaunchKernelGGL(k_prep,  dim3(48),   dim3(256), 0, stream, mem, inv32, bhi, blo);
  hipLaunchKernelGGL(k_main,  dim3(n_rows / 64), dim3(256), 0, stream,
                     x, mem, bhi, blo, out_near, flagbits);
  hipLaunchKernelGGL(k_copy,  dim3(2048), dim3(256), 0, stream,
                     x, out_x, n_rows * (DIM / 4));
  hipLaunchKernelGGL(k_refine, dim3(n_rows / 16), dim3(256), 0, stream,
                     x, mem, inv64, flagbits, out_near);
}

// Round 15
// 252.433 us; speedup vs baseline: 1.1825x; 1.1825x over previous
//
#include <hip/hip_runtime.h>

// Problem: nearest = memory[argmax_m cosine(x_row, memory_m)], plus copy of x.
//   x: 65536 x 1024 f32, memory: 40 x 1024 f32, out = [nearest | x-copy]
//
// R15 = R9 (best, 260us: MFMA split-f32, 1-deep A prefetch, B-first, nt
// stores) + B RELAYOUT to step-major: BH[T][m][32] / BL[T][m][32] so each
// per-step B-fragment load is 1KB FULLY CONTIGUOUS (8 full 128B lines) vs
// R9's row-major reads (16 half-used lines). TA line-touch model: B was 96
// of 160 line-events/step; this halves B's share (-30% total). R12/R13/R14
// falsified latency-depth, store-policy, and stream-mixing theories.
//
// d_ws layout (bytes):
//   [0,      320) : double inv64[40]
//   [320,    480) : float  inv32[40]
//   [512,  16896) : uint flagbits[4096]  (16-bit mask per 16-row wave)
//   [32768,131072): ushort BH[32][48][32] (bf16 hi of mem*inv32, step-major)
//   [131072,229376): ushort BL[32][48][32] (bf16 lo, step-major)

#define DIM 1024
#define NMEM 40

typedef float  vf4 __attribute__((ext_vector_type(4)));
typedef float  f4a __attribute__((ext_vector_type(4)));
typedef short  s8v __attribute__((ext_vector_type(8)));

union FragU { s8v v; unsigned int u[4]; };

constexpr float TAU = 2.5e-4f;   // normalized top-2 gap below which f64 re-resolve

// ---------------- Kernel 1: memory-row inverse norms (f32 + f64) ----------------
__global__ __launch_bounds__(64) void k_norms(const float* __restrict__ mem,
                                              double* __restrict__ inv64,
                                              float* __restrict__ inv32) {
  const int m = blockIdx.x;      // 40 blocks, 1 wave each
  const int lane = threadIdx.x;
  const float* __restrict__ row = mem + (size_t)m * DIM;
  double s = 0.0;
#pragma unroll
  for (int i = 0; i < DIM / 64; ++i) {
    double v = (double)row[lane + 64 * i];
    s = fma(v, v, s);
  }
#pragma unroll
  for (int off = 32; off > 0; off >>= 1) s += __shfl_xor(s, off, 64);
  if (lane == 0) {
    double n = sqrt(s);
    n = (n > 1e-8) ? n : 1e-8;
    inv64[m] = 1.0 / n;
    inv32[m] = (float)(1.0 / n);
  }
}

// ------------- Kernel 1b: split normalized memory -> step-major bf16 hi/lo -------------
// BH[T][m][k'] with T = k/32, k' = k%32: fragment rows for one K-step are
// contiguous -> each k_main B-load instruction covers 1KB of full lines.
__global__ __launch_bounds__(256) void k_prep(const float* __restrict__ mem,
                                              const float* __restrict__ inv32,
                                              unsigned short* __restrict__ BH,
                                              unsigned short* __restrict__ BL) {
  const int m = blockIdx.x;            // 0..47 (40 real + 8 zero-pad)
  const int k0 = threadIdx.x * 4;      // 1024/256 = 4 elems/thread
#pragma unroll
  for (int j = 0; j < 4; ++j) {
    const int k = k0 + j;
    const size_t dst = (size_t)(k >> 5) * (48 * 32) + (size_t)m * 32 + (k & 31);
    if (m < NMEM) {
      const float s = inv32[m];
      float w = mem[(size_t)m * DIM + k] * s;
      unsigned int u = __builtin_bit_cast(unsigned int, w);
      BH[dst] = (unsigned short)(u >> 16);
      float hf = __builtin_bit_cast(float, u & 0xFFFF0000u);
      float lo = w - hf;
      BL[dst] = (unsigned short)(__builtin_bit_cast(unsigned int, lo) >> 16);
    } else {
      BH[dst] = 0;
      BL[dst] = 0;
    }
  }
}

// ---------------- Kernel 2: MFMA sims + argmax + gather + x-copy ----------------
// Block = 256 thr = 4 independent waves (no barriers). Wave = 16 x-rows.
// A-frag (x): lane holds row (l&15), k-slice (l>>4)*8..+8. B-frag: lane holds
// m-col (l&15)+16*tile, same k-slice -> with step-major layout the load is
// BH + T*1536 + tt*512 + row*32 + kg*8 (contiguous 1KB per instruction).
// C layout (m89-verified): lane holds D[(l>>4)*4+j][(l&15)+16*tile].
__global__ __launch_bounds__(256, 4) void k_main(const float* __restrict__ x,
                                                 const float* __restrict__ mem,
                                                 const unsigned short* __restrict__ BH,
                                                 const unsigned short* __restrict__ BL,
                                                 float* __restrict__ out_near,
                                                 float* __restrict__ out_x,
                                                 unsigned int* __restrict__ flagbits) {
  __shared__ float nxw[4][16];
  __shared__ int   amaxw[4][16];
  __shared__ int   flagw[4][16];

  const int tid  = threadIdx.x;
  const int lane = tid & 63;
  const int w    = __builtin_amdgcn_readfirstlane(tid >> 6);
  const int row  = lane & 15;          // x-row within wave tile / m-col within tile
  const int kg   = lane >> 4;          // k-subslice group (0..3)
  const int rowbase = blockIdx.x * 64 + w * 16;

  const float* __restrict__ xp  = x     + (size_t)(rowbase + row) * DIM + kg * 8;
  float* __restrict__ oxp       = out_x + (size_t)(rowbase + row) * DIM + kg * 8;
  const unsigned short* __restrict__ bp = BH + row * 32 + kg * 8;  // + T*1536 + tt*512
  const unsigned short* __restrict__ lp = BL + row * 32 + kg * 8;

  f4a acc[3];
#pragma unroll
  for (int t = 0; t < 3; ++t) acc[t] = (f4a){0.f, 0.f, 0.f, 0.f};
  float nx = 0.f;

  vf4 cA0, cA1, nA0, nA1;
  cA0 = *(const vf4*)(xp);
  cA1 = *(const vf4*)(xp + 4);

  auto step = [&](vf4& a0, vf4& a1, vf4& n0, vf4& n1, int t) {
    // B-frags: step-major, contiguous 1KB per load
    s8v bh[3], bl[3];
#pragma unroll
    for (int tt = 0; tt < 3; ++tt) {
      bh[tt] = *(const s8v*)(bp + (size_t)t * 1536 + tt * 512);
      bl[tt] = *(const s8v*)(lp + (size_t)t * 1536 + tt * 512);
    }
    if (t < 31) {                       // A prefetch (HBM) into alternate regs
      n0 = *(const vf4*)(xp + (t + 1) * 32);
      n1 = *(const vf4*)(xp + (t + 1) * 32 + 4);
    }
    // x-copy from the same registers (x read exactly once)
    __builtin_nontemporal_store(a0, (vf4*)(oxp + t * 32));
    __builtin_nontemporal_store(a1, (vf4*)(oxp + t * 32 + 4));
    // ||x||^2 partial
    nx = fmaf(a0.x, a0.x, fmaf(a0.y, a0.y, fmaf(a0.z, a0.z, fmaf(a0.w, a0.w, nx))));
    nx = fmaf(a1.x, a1.x, fmaf(a1.y, a1.y, fmaf(a1.z, a1.z, fmaf(a1.w, a1.w, nx))));
    // split f32 -> hi/lo bf16 (truncation; residual ~2^-17)
    FragU ah, al;
    {
      float f[8] = {a0.x, a0.y, a0.z, a0.w, a1.x, a1.y, a1.z, a1.w};
#pragma unroll
      for (int p = 0; p < 4; ++p) {
        unsigned int u0 = __builtin_bit_cast(unsigned int, f[2 * p]);
        unsigned int u1 = __builtin_bit_cast(unsigned int, f[2 * p + 1]);
        ah.u[p] = (u1 & 0xFFFF0000u) | (u0 >> 16);
        float h0 = __builtin_bit_cast(float, u0 & 0xFFFF0000u);
        float h1 = __builtin_bit_cast(float, u1 & 0xFFFF0000u);
        float l0 = f[2 * p] - h0;
        float l1 = f[2 * p + 1] - h1;
        al.u[p] = (__builtin_bit_cast(unsigned int, l1) & 0xFFFF0000u) |
                  (__builtin_bit_cast(unsigned int, l0) >> 16);
      }
    }
    // 4 split passes x 3 N-tiles
#pragma unroll
    for (int tt = 0; tt < 3; ++tt) {
      acc[tt] = __builtin_amdgcn_mfma_f32_16x16x32_bf16(ah.v, bh[tt], acc[tt], 0, 0, 0);
      acc[tt] = __builtin_amdgcn_mfma_f32_16x16x32_bf16(ah.v, bl[tt], acc[tt], 0, 0, 0);
      acc[tt] = __builtin_amdgcn_mfma_f32_16x16x32_bf16(al.v, bh[tt], acc[tt], 0, 0, 0);
      acc[tt] = __builtin_amdgcn_mfma_f32_16x16x32_bf16(al.v, bl[tt], acc[tt], 0, 0, 0);
    }
  };

  for (int t = 0; t < 32; t += 2) {     // explicit double-buffer, static indexing
    step(cA0, cA1, nA0, nA1, t);
    step(nA0, nA1, cA0, cA1, t + 1);
  }

  // ||x||^2: sum the 4 k-groups (lanes l, l^16, l^32, l^48 share row l&15)
  nx += __shfl_xor(nx, 16, 64);
  nx += __shfl_xor(nx, 32, 64);
  if (lane < 16) nxw[w][lane] = nx;

  // per-lane top-2: lane holds sims for rows (l>>4)*4+j, m-cols (l&15)+16t
  float v1[4], v2[4];
  int   i1[4];
#pragma unroll
  for (int j = 0; j < 4; ++j) {
    float c0 = acc[0][j], c1 = acc[1][j];
    float c2 = (row < 8) ? acc[2][j] : -3.4e38f;   // cols 40-47 are pad
    float a1 = c0, a2 = -3.4e38f;
    int   ai = row;
    if (c1 > a1) { a2 = a1; a1 = c1; ai = row + 16; } else a2 = c1;
    if (c2 > a1) { a2 = a1; a1 = c2; ai = row + 32; } else if (c2 > a2) a2 = c2;
    v1[j] = a1; v2[j] = a2; i1[j] = ai;
  }
#pragma unroll
  for (int st = 1; st < 16; st <<= 1) {  // reduce over the 16 lanes of each row-group
#pragma unroll
    for (int j = 0; j < 4; ++j) {
      float o1 = __shfl_xor(v1[j], st, 64);
      float o2 = __shfl_xor(v2[j], st, 64);
      int   oi = __shfl_xor(i1[j], st, 64);
      if (o1 > v1[j]) { v2[j] = fmaxf(v1[j], o2); v1[j] = o1; i1[j] = oi; }
      else            { v2[j] = fmaxf(v2[j], o1); }           // tie -> gap 0 -> flagged
    }
  }
  if ((lane & 15) == 0) {
    const int g = lane >> 4;
#pragma unroll
    for (int j = 0; j < 4; ++j) {
      const int r = 4 * g + j;
      float gap = (v1[j] - v2[j]) * rsqrtf(fmaxf(nxw[w][r], 1e-30f));
      flagw[w][r] = !(gap >= TAU);     // NaN-safe
      amaxw[w][r] = i1[j];
    }
  }
  int flv = flagw[w][lane & 15];
  unsigned long long bmask = __ballot(flv != 0);
  if (lane == 0) flagbits[blockIdx.x * 4 + w] = (unsigned int)(bmask & 0xFFFFull);

  // gather-copy memory[amax] -> out_near (16 rows/wave, coalesced; nt OK:
  // 64 lanes x 16B contiguous = full lines per instruction)
  const vf4* __restrict__ m4 = (const vf4*)mem;
#pragma unroll 1
  for (int r = 0; r < 16; ++r) {
    int am = __builtin_amdgcn_readfirstlane(amaxw[w][r]);
    const vf4* __restrict__ src = m4 + (size_t)am * (DIM / 4);
    vf4* __restrict__ dst = (vf4*)out_near + (size_t)(rowbase + r) * (DIM / 4);
#pragma unroll
    for (int j = 0; j < 4; ++j) {
      vf4 v = src[lane + 64 * j];
      __builtin_nontemporal_store(v, &dst[lane + 64 * j]);
    }
  }
}

// ---------------- Kernel 3: f64 re-resolution of razor-thin rows ----------------
__global__ __launch_bounds__(256) void k_refine(const float* __restrict__ x,
                                                const float* __restrict__ mem,
                                                const double* __restrict__ inv64,
                                                const unsigned int* __restrict__ flagbits,
                                                float* __restrict__ out_near) {
  unsigned int mask = flagbits[blockIdx.x];
  if (mask == 0u) return;                   // uniform; nearly all blocks exit
  const int tid = threadIdx.x;
  const int lane = tid & 63;
  const int wid = tid >> 6;
  __shared__ double bval[4];
  __shared__ int bidx[4];
  while (mask) {
    int r = __ffs(mask) - 1;
    mask &= (mask - 1u);
    int rrow = blockIdx.x * 16 + r;
    const float* __restrict__ xr = x + (size_t)rrow * DIM;
    double xd[16];
#pragma unroll
    for (int i = 0; i < 16; ++i) xd[i] = (double)xr[lane + 64 * i];
    double best = -1e300;
    int bi = 0;
    for (int q = 0; q < 10; ++q) {
      int m = wid * 10 + q;
      const float* __restrict__ mr = mem + (size_t)m * DIM;
      double s = 0.0;
#pragma unroll
      for (int i = 0; i < 16; ++i) s = fma(xd[i], (double)mr[lane + 64 * i], s);
#pragma unroll
      for (int off = 32; off > 0; off >>= 1) s += __shfl_xor(s, off, 64);
      double v = s * inv64[m];              // identical (bitwise) across lanes
      if (v > best) { best = v; bi = m; }   // strict > keeps lowest m on ties
    }
    if (lane == 0) { bval[wid] = best; bidx[wid] = bi; }
    __syncthreads();
    double g = bval[0];
    int gi = bidx[0];
#pragma unroll
    for (int gg = 1; gg < 4; ++gg) {
      if (bval[gg] > g) { g = bval[gg]; gi = bidx[gg]; }
    }
    const float4* __restrict__ src = (const float4*)mem + (size_t)gi * (DIM / 4);
    float4* __restrict__ dst = (float4*)out_near + (size_t)rrow * (DIM / 4);
    dst[tid] = src[tid];                    // 256 x 16B = full row, coalesced
    __syncthreads();                        // LDS reuse guard for next flagged row
  }
}

extern "C" void kernel_launch(void* const* d_in, const int* in_sizes, int n_in,
                              void* d_out, int out_size, void* d_ws, size_t ws_size,
                              hipStream_t stream) {
  const float* x   = (const float*)d_in[0];
  const float* mem = (const float*)d_in[1];
  // d_in[2] = top_k (unused: reference only consumes idx[:,0], i.e. the argmax)

  const int n_rows = in_sizes[0] / DIM;          // 65536
  float* out_near = (float*)d_out;
  float* out_x    = (float*)d_out + (size_t)n_rows * DIM;

  double* inv64 = (double*)d_ws;
  float*  inv32 = (float*)((char*)d_ws + 320);
  unsigned int* flagbits = (unsigned int*)((char*)d_ws + 512);
  unsigned short* BH = (unsigned short*)((char*)d_ws + 32768);
  unsigned short* BL = (unsigned short*)((char*)d_ws + 131072);

  hipLaunchKernelGGL(k_norms, dim3(NMEM), dim3(64), 0, stream, mem, inv64, inv32);
  hipLaunchKernelGGL(k_prep,  dim3(48),   dim3(256), 0, stream, mem, inv32, BH, BL);
  hipLaunchKernelGGL(k_main,  dim3(n_rows / 64), dim3(256), 0, stream,
                     x, mem, BH, BL, out_near, out_x, flagbits);
  hipLaunchKernelGGL(k_refine, dim3(n_rows / 16), dim3(256), 0, stream,
                     x, mem, inv64, flagbits, out_near);
}

// Round 16
// 241.135 us; speedup vs baseline: 1.2379x; 1.0469x over previous
//
#include <hip/hip_runtime.h>

// Problem: nearest = memory[argmax_m cosine(x_row, memory_m)], plus copy of x.
//   x: 65536 x 1024 f32, memory: 40 x 1024 f32, out = [nearest | x-copy]
//
// R16 = R15 (best, 252us: MFMA split-f32, step-major B, nt stores) + K-PHASE
// ROTATION: block/wave (b,w) starts its K-loop at t0=(5b+8w)&31 and wraps.
// Theory: A-reads/stores hit 16 rows x 128B at 4KB stride, SAME offset t*128
// in every row -> same HBM channel; with every wave chip-wide on the same
// t-schedule, the chip hammers a few channels (~1-2 TB/s observed, vs 6.6
// TB/s fill). Rotation spreads concurrent traffic across all 32 offsets.
// K-sum is commutative; sims shift by ~1e-6 (f32 reassoc) << TAU margin, and
// the f64 refine net keeps the argmax exact.
//
// d_ws layout (bytes):
//   [0,      320) : double inv64[40]
//   [320,    480) : float  inv32[40]
//   [512,  16896) : uint flagbits[4096]  (16-bit mask per 16-row wave)
//   [32768,131072): ushort BH[32][48][32] (bf16 hi of mem*inv32, step-major)
//   [131072,229376): ushort BL[32][48][32] (bf16 lo, step-major)

#define DIM 1024
#define NMEM 40

typedef float  vf4 __attribute__((ext_vector_type(4)));
typedef float  f4a __attribute__((ext_vector_type(4)));
typedef short  s8v __attribute__((ext_vector_type(8)));

union FragU { s8v v; unsigned int u[4]; };

constexpr float TAU = 2.5e-4f;   // normalized top-2 gap below which f64 re-resolve

// ---------------- Kernel 1: memory-row inverse norms (f32 + f64) ----------------
__global__ __launch_bounds__(64) void k_norms(const float* __restrict__ mem,
                                              double* __restrict__ inv64,
                                              float* __restrict__ inv32) {
  const int m = blockIdx.x;      // 40 blocks, 1 wave each
  const int lane = threadIdx.x;
  const float* __restrict__ row = mem + (size_t)m * DIM;
  double s = 0.0;
#pragma unroll
  for (int i = 0; i < DIM / 64; ++i) {
    double v = (double)row[lane + 64 * i];
    s = fma(v, v, s);
  }
#pragma unroll
  for (int off = 32; off > 0; off >>= 1) s += __shfl_xor(s, off, 64);
  if (lane == 0) {
    double n = sqrt(s);
    n = (n > 1e-8) ? n : 1e-8;
    inv64[m] = 1.0 / n;
    inv32[m] = (float)(1.0 / n);
  }
}

// ------------- Kernel 1b: split normalized memory -> step-major bf16 hi/lo -------------
__global__ __launch_bounds__(256) void k_prep(const float* __restrict__ mem,
                                              const float* __restrict__ inv32,
                                              unsigned short* __restrict__ BH,
                                              unsigned short* __restrict__ BL) {
  const int m = blockIdx.x;            // 0..47 (40 real + 8 zero-pad)
  const int k0 = threadIdx.x * 4;      // 1024/256 = 4 elems/thread
#pragma unroll
  for (int j = 0; j < 4; ++j) {
    const int k = k0 + j;
    const size_t dst = (size_t)(k >> 5) * (48 * 32) + (size_t)m * 32 + (k & 31);
    if (m < NMEM) {
      const float s = inv32[m];
      float w = mem[(size_t)m * DIM + k] * s;
      unsigned int u = __builtin_bit_cast(unsigned int, w);
      BH[dst] = (unsigned short)(u >> 16);
      float hf = __builtin_bit_cast(float, u & 0xFFFF0000u);
      float lo = w - hf;
      BL[dst] = (unsigned short)(__builtin_bit_cast(unsigned int, lo) >> 16);
    } else {
      BH[dst] = 0;
      BL[dst] = 0;
    }
  }
}

// ---------------- Kernel 2: MFMA sims + argmax + gather + x-copy ----------------
// Block = 256 thr = 4 independent waves (no barriers). Wave = 16 x-rows.
// A-frag (x): lane holds row (l&15), k-slice (l>>4)*8..+8. B-frag: step-major,
// contiguous 1KB per load. C layout (m89-verified): D[(l>>4)*4+j][(l&15)+16t].
// K-loop starts at t0=(5b+8w)&31 and wraps (channel de-phasing).
__global__ __launch_bounds__(256, 4) void k_main(const float* __restrict__ x,
                                                 const float* __restrict__ mem,
                                                 const unsigned short* __restrict__ BH,
                                                 const unsigned short* __restrict__ BL,
                                                 float* __restrict__ out_near,
                                                 float* __restrict__ out_x,
                                                 unsigned int* __restrict__ flagbits) {
  __shared__ float nxw[4][16];
  __shared__ int   amaxw[4][16];
  __shared__ int   flagw[4][16];

  const int tid  = threadIdx.x;
  const int lane = tid & 63;
  const int w    = __builtin_amdgcn_readfirstlane(tid >> 6);
  const int row  = lane & 15;          // x-row within wave tile / m-col within tile
  const int kg   = lane >> 4;          // k-subslice group (0..3)
  const int rowbase = blockIdx.x * 64 + w * 16;

  const float* __restrict__ xp  = x     + (size_t)(rowbase + row) * DIM + kg * 8;
  float* __restrict__ oxp       = out_x + (size_t)(rowbase + row) * DIM + kg * 8;
  const unsigned short* __restrict__ bp = BH + row * 32 + kg * 8;  // + t*1536 + tt*512
  const unsigned short* __restrict__ lp = BL + row * 32 + kg * 8;

  f4a acc[3];
#pragma unroll
  for (int t = 0; t < 3; ++t) acc[t] = (f4a){0.f, 0.f, 0.f, 0.f};
  float nx = 0.f;

  const int t0 = (blockIdx.x * 5 + w * 8) & 31;   // K-phase of this wave

  vf4 cA0, cA1, nA0, nA1;
  cA0 = *(const vf4*)(xp + t0 * 32);
  cA1 = *(const vf4*)(xp + t0 * 32 + 4);

  // step: consume (a0,a1) as K-step t; if pf, prefetch K-step tn into (n0,n1)
  auto step = [&](vf4& a0, vf4& a1, vf4& n0, vf4& n1, int t, int tn, bool pf) {
    // B-frags: step-major, contiguous 1KB per load (issue FIRST: B-first order)
    s8v bh[3], bl[3];
#pragma unroll
    for (int tt2 = 0; tt2 < 3; ++tt2) {
      bh[tt2] = *(const s8v*)(bp + (size_t)t * 1536 + tt2 * 512);
      bl[tt2] = *(const s8v*)(lp + (size_t)t * 1536 + tt2 * 512);
    }
    if (pf) {                           // A prefetch (HBM) into alternate regs
      n0 = *(const vf4*)(xp + tn * 32);
      n1 = *(const vf4*)(xp + tn * 32 + 4);
    }
    // x-copy from the same registers (x read exactly once)
    __builtin_nontemporal_store(a0, (vf4*)(oxp + t * 32));
    __builtin_nontemporal_store(a1, (vf4*)(oxp + t * 32 + 4));
    // ||x||^2 partial
    nx = fmaf(a0.x, a0.x, fmaf(a0.y, a0.y, fmaf(a0.z, a0.z, fmaf(a0.w, a0.w, nx))));
    nx = fmaf(a1.x, a1.x, fmaf(a1.y, a1.y, fmaf(a1.z, a1.z, fmaf(a1.w, a1.w, nx))));
    // split f32 -> hi/lo bf16 (truncation; residual ~2^-17)
    FragU ah, al;
    {
      float f[8] = {a0.x, a0.y, a0.z, a0.w, a1.x, a1.y, a1.z, a1.w};
#pragma unroll
      for (int p = 0; p < 4; ++p) {
        unsigned int u0 = __builtin_bit_cast(unsigned int, f[2 * p]);
        unsigned int u1 = __builtin_bit_cast(unsigned int, f[2 * p + 1]);
        ah.u[p] = (u1 & 0xFFFF0000u) | (u0 >> 16);
        float h0 = __builtin_bit_cast(float, u0 & 0xFFFF0000u);
        float h1 = __builtin_bit_cast(float, u1 & 0xFFFF0000u);
        float l0 = f[2 * p] - h0;
        float l1 = f[2 * p + 1] - h1;
        al.u[p] = (__builtin_bit_cast(unsigned int, l1) & 0xFFFF0000u) |
                  (__builtin_bit_cast(unsigned int, l0) >> 16);
      }
    }
    // 4 split passes x 3 N-tiles
#pragma unroll
    for (int tt2 = 0; tt2 < 3; ++tt2) {
      acc[tt2] = __builtin_amdgcn_mfma_f32_16x16x32_bf16(ah.v, bh[tt2], acc[tt2], 0, 0, 0);
      acc[tt2] = __builtin_amdgcn_mfma_f32_16x16x32_bf16(ah.v, bl[tt2], acc[tt2], 0, 0, 0);
      acc[tt2] = __builtin_amdgcn_mfma_f32_16x16x32_bf16(al.v, bh[tt2], acc[tt2], 0, 0, 0);
      acc[tt2] = __builtin_amdgcn_mfma_f32_16x16x32_bf16(al.v, bl[tt2], acc[tt2], 0, 0, 0);
    }
  };

  for (int tt = 0; tt < 32; tt += 2) {  // rotated K-loop, double-buffered regs
    step(cA0, cA1, nA0, nA1, (t0 + tt) & 31, (t0 + tt + 1) & 31, true);
    step(nA0, nA1, cA0, cA1, (t0 + tt + 1) & 31, (t0 + tt + 2) & 31, tt + 1 < 31);
  }

  // ||x||^2: sum the 4 k-groups (lanes l, l^16, l^32, l^48 share row l&15)
  nx += __shfl_xor(nx, 16, 64);
  nx += __shfl_xor(nx, 32, 64);
  if (lane < 16) nxw[w][lane] = nx;

  // per-lane top-2: lane holds sims for rows (l>>4)*4+j, m-cols (l&15)+16t
  float v1[4], v2[4];
  int   i1[4];
#pragma unroll
  for (int j = 0; j < 4; ++j) {
    float c0 = acc[0][j], c1 = acc[1][j];
    float c2 = (row < 8) ? acc[2][j] : -3.4e38f;   // cols 40-47 are pad
    float a1 = c0, a2 = -3.4e38f;
    int   ai = row;
    if (c1 > a1) { a2 = a1; a1 = c1; ai = row + 16; } else a2 = c1;
    if (c2 > a1) { a2 = a1; a1 = c2; ai = row + 32; } else if (c2 > a2) a2 = c2;
    v1[j] = a1; v2[j] = a2; i1[j] = ai;
  }
#pragma unroll
  for (int st = 1; st < 16; st <<= 1) {  // reduce over the 16 lanes of each row-group
#pragma unroll
    for (int j = 0; j < 4; ++j) {
      float o1 = __shfl_xor(v1[j], st, 64);
      float o2 = __shfl_xor(v2[j], st, 64);
      int   oi = __shfl_xor(i1[j], st, 64);
      if (o1 > v1[j]) { v2[j] = fmaxf(v1[j], o2); v1[j] = o1; i1[j] = oi; }
      else            { v2[j] = fmaxf(v2[j], o1); }           // tie -> gap 0 -> flagged
    }
  }
  if ((lane & 15) == 0) {
    const int g = lane >> 4;
#pragma unroll
    for (int j = 0; j < 4; ++j) {
      const int r = 4 * g + j;
      float gap = (v1[j] - v2[j]) * rsqrtf(fmaxf(nxw[w][r], 1e-30f));
      flagw[w][r] = !(gap >= TAU);     // NaN-safe
      amaxw[w][r] = i1[j];
    }
  }
  int flv = flagw[w][lane & 15];
  unsigned long long bmask = __ballot(flv != 0);
  if (lane == 0) flagbits[blockIdx.x * 4 + w] = (unsigned int)(bmask & 0xFFFFull);

  // gather-copy memory[amax] -> out_near (16 rows/wave, coalesced; nt OK:
  // 64 lanes x 16B contiguous = full lines per instruction)
  const vf4* __restrict__ m4 = (const vf4*)mem;
#pragma unroll 1
  for (int r = 0; r < 16; ++r) {
    int am = __builtin_amdgcn_readfirstlane(amaxw[w][r]);
    const vf4* __restrict__ src = m4 + (size_t)am * (DIM / 4);
    vf4* __restrict__ dst = (vf4*)out_near + (size_t)(rowbase + r) * (DIM / 4);
#pragma unroll
    for (int j = 0; j < 4; ++j) {
      vf4 v = src[lane + 64 * j];
      __builtin_nontemporal_store(v, &dst[lane + 64 * j]);
    }
  }
}

// ---------------- Kernel 3: f64 re-resolution of razor-thin rows ----------------
__global__ __launch_bounds__(256) void k_refine(const float* __restrict__ x,
                                                const float* __restrict__ mem,
                                                const double* __restrict__ inv64,
                                                const unsigned int* __restrict__ flagbits,
                                                float* __restrict__ out_near) {
  unsigned int mask = flagbits[blockIdx.x];
  if (mask == 0u) return;                   // uniform; nearly all blocks exit
  const int tid = threadIdx.x;
  const int lane = tid & 63;
  const int wid = tid >> 6;
  __shared__ double bval[4];
  __shared__ int bidx[4];
  while (mask) {
    int r = __ffs(mask) - 1;
    mask &= (mask - 1u);
    int rrow = blockIdx.x * 16 + r;
    const float* __restrict__ xr = x + (size_t)rrow * DIM;
    double xd[16];
#pragma unroll
    for (int i = 0; i < 16; ++i) xd[i] = (double)xr[lane + 64 * i];
    double best = -1e300;
    int bi = 0;
    for (int q = 0; q < 10; ++q) {
      int m = wid * 10 + q;
      const float* __restrict__ mr = mem + (size_t)m * DIM;
      double s = 0.0;
#pragma unroll
      for (int i = 0; i < 16; ++i) s = fma(xd[i], (double)mr[lane + 64 * i], s);
#pragma unroll
      for (int off = 32; off > 0; off >>= 1) s += __shfl_xor(s, off, 64);
      double v = s * inv64[m];              // identical (bitwise) across lanes
      if (v > best) { best = v; bi = m; }   // strict > keeps lowest m on ties
    }
    if (lane == 0) { bval[wid] = best; bidx[wid] = bi; }
    __syncthreads();
    double g = bval[0];
    int gi = bidx[0];
#pragma unroll
    for (int gg = 1; gg < 4; ++gg) {
      if (bval[gg] > g) { g = bval[gg]; gi = bidx[gg]; }
    }
    const float4* __restrict__ src = (const float4*)mem + (size_t)gi * (DIM / 4);
    float4* __restrict__ dst = (float4*)out_near + (size_t)rrow * (DIM / 4);
    dst[tid] = src[tid];                    // 256 x 16B = full row, coalesced
    __syncthreads();                        // LDS reuse guard for next flagged row
  }
}

extern "C" void kernel_launch(void* const* d_in, const int* in_sizes, int n_in,
                              void* d_out, int out_size, void* d_ws, size_t ws_size,
                              hipStream_t stream) {
  const float* x   = (const float*)d_in[0];
  const float* mem = (const float*)d_in[1];
  // d_in[2] = top_k (unused: reference only consumes idx[:,0], i.e. the argmax)

  const int n_rows = in_sizes[0] / DIM;          // 65536
  float* out_near = (float*)d_out;
  float* out_x    = (float*)d_out + (size_t)n_rows * DIM;

  double* inv64 = (double*)d_ws;
  float*  inv32 = (float*)((char*)d_ws + 320);
  unsigned int* flagbits = (unsigned int*)((char*)d_ws + 512);
  unsigned short* BH = (unsigned short*)((char*)d_ws + 32768);
  unsigned short* BL = (unsigned short*)((char*)d_ws + 131072);

  hipLaunchKernelGGL(k_norms, dim3(NMEM), dim3(64), 0, stream, mem, inv64, inv32);
  hipLaunchKernelGGL(k_prep,  dim3(48),   dim3(256), 0, stream, mem, inv32, BH, BL);
  hipLaunchKernelGGL(k_main,  dim3(n_rows / 64), dim3(256), 0, stream,
                     x, mem, BH, BL, out_near, out_x, flagbits);
  hipLaunchKernelGGL(k_refine, dim3(n_rows / 16), dim3(256), 0, stream,
                     x, mem, inv64, flagbits, out_near);
}

// Round 18
// 197.918 us; speedup vs baseline: 1.5082x; 1.2184x over previous
//
#include <hip/hip_runtime.h>

// Problem: nearest = memory[argmax_m cosine(x_row, memory_m)], plus copy of x.
//   x: 65536 x 1024 f32, memory: 40 x 1024 f32, out = [nearest | x-copy]
//
// R18 = R17 with the flag-redistribution shfl bug fixed (R17 shfl'd a
// lane-dependent SELECT, so every row got its group's fl0; now each flag
// register is shfl'd individually and selected on the READING lane).
// R17 structure: every HBM instruction 1KB contiguous (row-at-a-time A
// staging + nt x-copy from same regs + wave-private XOR-swizzled LDS),
// zero barriers, step-major B, K-quarter rotation for chip-wide de-phasing.
//
// d_ws layout (bytes):
//   [0,      320) : double inv64[40]
//   [320,    480) : float  inv32[40]
//   [512,  16896) : uint flagbits[4096]  (16-bit mask per 16-row wave)
//   [32768,131072): ushort BH[32][48][32] (bf16 hi of mem*inv32, step-major)
//   [131072,229376): ushort BL[32][48][32] (bf16 lo, step-major)

#define DIM 1024
#define NMEM 40

typedef float  vf4 __attribute__((ext_vector_type(4)));
typedef float  f4a __attribute__((ext_vector_type(4)));
typedef short  s8v __attribute__((ext_vector_type(8)));

union FragU { s8v v; unsigned int u[4]; };

constexpr float TAU = 2.5e-4f;   // normalized top-2 gap below which f64 re-resolve

// ---------------- Kernel 1: memory-row inverse norms (f32 + f64) ----------------
__global__ __launch_bounds__(64) void k_norms(const float* __restrict__ mem,
                                              double* __restrict__ inv64,
                                              float* __restrict__ inv32) {
  const int m = blockIdx.x;      // 40 blocks, 1 wave each
  const int lane = threadIdx.x;
  const float* __restrict__ row = mem + (size_t)m * DIM;
  double s = 0.0;
#pragma unroll
  for (int i = 0; i < DIM / 64; ++i) {
    double v = (double)row[lane + 64 * i];
    s = fma(v, v, s);
  }
#pragma unroll
  for (int off = 32; off > 0; off >>= 1) s += __shfl_xor(s, off, 64);
  if (lane == 0) {
    double n = sqrt(s);
    n = (n > 1e-8) ? n : 1e-8;
    inv64[m] = 1.0 / n;
    inv32[m] = (float)(1.0 / n);
  }
}

// ------------- Kernel 1b: split normalized memory -> step-major bf16 hi/lo -------------
__global__ __launch_bounds__(256) void k_prep(const float* __restrict__ mem,
                                              const float* __restrict__ inv32,
                                              unsigned short* __restrict__ BH,
                                              unsigned short* __restrict__ BL) {
  const int m = blockIdx.x;            // 0..47 (40 real + 8 zero-pad)
  const int k0 = threadIdx.x * 4;      // 1024/256 = 4 elems/thread
#pragma unroll
  for (int j = 0; j < 4; ++j) {
    const int k = k0 + j;
    const size_t dst = (size_t)(k >> 5) * (48 * 32) + (size_t)m * 32 + (k & 31);
    if (m < NMEM) {
      const float s = inv32[m];
      float w = mem[(size_t)m * DIM + k] * s;
      unsigned int u = __builtin_bit_cast(unsigned int, w);
      BH[dst] = (unsigned short)(u >> 16);
      float hf = __builtin_bit_cast(float, u & 0xFFFF0000u);
      float lo = w - hf;
      BL[dst] = (unsigned short)(__builtin_bit_cast(unsigned int, lo) >> 16);
    } else {
      BH[dst] = 0;
      BL[dst] = 0;
    }
  }
}

// ---------------- Kernel 2: MFMA sims + argmax + gather + x-copy ----------------
// Block = 256 thr = 4 independent waves (no barriers). Wave = 16 x-rows.
// Per K-quarter q: stage 16 rows (1KB-contiguous load + 1KB-contiguous nt
// x-copy store + swizzled ds_write per row), then 8 steps of {B-loads (1KB
// contiguous L2), A-frags from LDS, split, 12 MFMA}. C layout (m89-verified):
// lane holds D[(l>>4)*4+j][(l&15)+16*tile].
__global__ __launch_bounds__(256, 2) void k_main(const float* __restrict__ x,
                                                 const float* __restrict__ mem,
                                                 const unsigned short* __restrict__ BH,
                                                 const unsigned short* __restrict__ BL,
                                                 float* __restrict__ out_near,
                                                 float* __restrict__ out_x,
                                                 unsigned int* __restrict__ flagbits) {
  __shared__ vf4 xq4[4 * 16 * 64];     // exactly 64 KB: wave w owns [w*1024, w*1024+1024)

  const int tid  = threadIdx.x;
  const int lane = tid & 63;
  const int w    = __builtin_amdgcn_readfirstlane(tid >> 6);
  const int row  = lane & 15;          // x-row within wave tile / m-col within tile
  const int kg   = lane >> 4;          // k-subslice group (0..3)
  const int rowbase = blockIdx.x * 64 + w * 16;

  const unsigned short* __restrict__ bp = BH + row * 32 + kg * 8;  // + T*1536 + tt*512
  const unsigned short* __restrict__ lp = BL + row * 32 + kg * 8;

  f4a acc[3];
#pragma unroll
  for (int t = 0; t < 3; ++t) acc[t] = (f4a){0.f, 0.f, 0.f, 0.f};
  float nx = 0.f;

  const int q0 = (blockIdx.x + w) & 3;   // quarter-phase rotation (R16 de-phasing)
  vf4* __restrict__ xw = xq4 + w * 1024;

#pragma unroll 1
  for (int qq = 0; qq < 4; ++qq) {
    const int q = (q0 + qq) & 3;
    // ---- stage quarter q: 16 rows, each 1KB contiguous (load + nt-store + ds_write) ----
#pragma unroll 4
    for (int r = 0; r < 16; ++r) {
      const float* __restrict__ src = x + (size_t)(rowbase + r) * DIM + q * 256;
      float* __restrict__ dst       = out_x + (size_t)(rowbase + r) * DIM + q * 256;
      vf4 v = *(const vf4*)(src + lane * 4);
      __builtin_nontemporal_store(v, (vf4*)(dst + lane * 4));   // x-copy, 1KB contiguous
      xw[r * 64 + (lane ^ (r & 7))] = v;                        // XOR-swizzled (conflict-min)
    }
    // ---- compute 8 K-steps of this quarter ----
#pragma unroll
    for (int tl = 0; tl < 8; ++tl) {
      const int T = q * 8 + tl;
      s8v bh[3], bl[3];                 // B first (issue order; L2, 1KB contiguous)
#pragma unroll
      for (int tt = 0; tt < 3; ++tt) {
        bh[tt] = *(const s8v*)(bp + (size_t)T * 1536 + tt * 512);
        bl[tt] = *(const s8v*)(lp + (size_t)T * 1536 + tt * 512);
      }
      const int f = tl * 8 + kg * 2;
      vf4 a0 = xw[row * 64 + (f ^ (row & 7))];
      vf4 a1 = xw[row * 64 + ((f + 1) ^ (row & 7))];
      nx = fmaf(a0.x, a0.x, fmaf(a0.y, a0.y, fmaf(a0.z, a0.z, fmaf(a0.w, a0.w, nx))));
      nx = fmaf(a1.x, a1.x, fmaf(a1.y, a1.y, fmaf(a1.z, a1.z, fmaf(a1.w, a1.w, nx))));
      FragU ah, al;
      {
        float fbuf[8] = {a0.x, a0.y, a0.z, a0.w, a1.x, a1.y, a1.z, a1.w};
#pragma unroll
        for (int p = 0; p < 4; ++p) {
          unsigned int u0 = __builtin_bit_cast(unsigned int, fbuf[2 * p]);
          unsigned int u1 = __builtin_bit_cast(unsigned int, fbuf[2 * p + 1]);
          ah.u[p] = (u1 & 0xFFFF0000u) | (u0 >> 16);
          float h0 = __builtin_bit_cast(float, u0 & 0xFFFF0000u);
          float h1 = __builtin_bit_cast(float, u1 & 0xFFFF0000u);
          float l0 = fbuf[2 * p] - h0;
          float l1 = fbuf[2 * p + 1] - h1;
          al.u[p] = (__builtin_bit_cast(unsigned int, l1) & 0xFFFF0000u) |
                    (__builtin_bit_cast(unsigned int, l0) >> 16);
        }
      }
#pragma unroll
      for (int tt = 0; tt < 3; ++tt) {
        acc[tt] = __builtin_amdgcn_mfma_f32_16x16x32_bf16(ah.v, bh[tt], acc[tt], 0, 0, 0);
        acc[tt] = __builtin_amdgcn_mfma_f32_16x16x32_bf16(ah.v, bl[tt], acc[tt], 0, 0, 0);
        acc[tt] = __builtin_amdgcn_mfma_f32_16x16x32_bf16(al.v, bh[tt], acc[tt], 0, 0, 0);
        acc[tt] = __builtin_amdgcn_mfma_f32_16x16x32_bf16(al.v, bl[tt], acc[tt], 0, 0, 0);
      }
    }
  }

  // ||x||^2: sum the 4 k-groups (lanes l, l^16, l^32, l^48 share row l&15)
  nx += __shfl_xor(nx, 16, 64);
  nx += __shfl_xor(nx, 32, 64);
  // now every lane: nx = ||x_{row=lane&15}||^2

  // per-lane top-2: lane holds sims for rows (l>>4)*4+j, m-cols (l&15)+16t
  float v1[4], v2[4];
  int   i1[4];
#pragma unroll
  for (int j = 0; j < 4; ++j) {
    float c0 = acc[0][j], c1 = acc[1][j];
    float c2 = (row < 8) ? acc[2][j] : -3.4e38f;   // cols 40-47 are pad
    float a1 = c0, a2 = -3.4e38f;
    int   ai = row;
    if (c1 > a1) { a2 = a1; a1 = c1; ai = row + 16; } else a2 = c1;
    if (c2 > a1) { a2 = a1; a1 = c2; ai = row + 32; } else if (c2 > a2) a2 = c2;
    v1[j] = a1; v2[j] = a2; i1[j] = ai;
  }
#pragma unroll
  for (int st = 1; st < 16; st <<= 1) {  // butterfly: 16 lanes of each group converge
#pragma unroll
    for (int j = 0; j < 4; ++j) {
      float o1 = __shfl_xor(v1[j], st, 64);
      float o2 = __shfl_xor(v2[j], st, 64);
      int   oi = __shfl_xor(i1[j], st, 64);
      if (o1 > v1[j]) { v2[j] = fmaxf(v1[j], o2); v1[j] = o1; i1[j] = oi; }
      else            { v2[j] = fmaxf(v2[j], o1); }           // tie -> gap 0 -> flagged
    }
  }
  // flags: group g (= lane>>4) holds rows 4g+j; nx fetched from row-owner lane
  const int g = lane >> 4;
  float nx0 = __shfl(nx, 4 * g + 0, 64);
  float nx1 = __shfl(nx, 4 * g + 1, 64);
  float nx2 = __shfl(nx, 4 * g + 2, 64);
  float nx3 = __shfl(nx, 4 * g + 3, 64);
  int fl0 = !((v1[0] - v2[0]) * rsqrtf(fmaxf(nx0, 1e-30f)) >= TAU);  // NaN-safe
  int fl1 = !((v1[1] - v2[1]) * rsqrtf(fmaxf(nx1, 1e-30f)) >= TAU);
  int fl2 = !((v1[2] - v2[2]) * rsqrtf(fmaxf(nx2, 1e-30f)) >= TAU);
  int fl3 = !((v1[3] - v2[3]) * rsqrtf(fmaxf(nx3, 1e-30f)) >= TAU);
  // redistribute (R17 BUGFIX): shfl each flag register individually from the
  // row-owner group's lane 0, then select with the READING lane's j.
  const int srcl = 16 * ((lane & 15) >> 2);
  int f0 = __shfl(fl0, srcl, 64);
  int f1 = __shfl(fl1, srcl, 64);
  int f2 = __shfl(fl2, srcl, 64);
  int f3 = __shfl(fl3, srcl, 64);
  const int jsel = lane & 3;
  int flv = (jsel & 2) ? ((jsel & 1) ? f3 : f2) : ((jsel & 1) ? f1 : f0);
  unsigned long long bmask = __ballot(flv != 0);
  if (lane == 0) flagbits[blockIdx.x * 4 + w] = (unsigned int)(bmask & 0xFFFFull);

  // gather-copy memory[amax] -> out_near (16 rows/wave, coalesced nt full lines)
  // (i1[r&3] is compile-time-indexed on BOTH sides of the shfl -> correct)
  const vf4* __restrict__ m4 = (const vf4*)mem;
#pragma unroll
  for (int r = 0; r < 16; ++r) {
    int am = __shfl(i1[r & 3], 16 * (r >> 2), 64);
    am = __builtin_amdgcn_readfirstlane(am);
    const vf4* __restrict__ src = m4 + (size_t)am * (DIM / 4);
    vf4* __restrict__ dst = (vf4*)out_near + (size_t)(rowbase + r) * (DIM / 4);
#pragma unroll
    for (int j = 0; j < 4; ++j) {
      vf4 v = src[lane + 64 * j];
      __builtin_nontemporal_store(v, &dst[lane + 64 * j]);
    }
  }
}

// ---------------- Kernel 3: f64 re-resolution of razor-thin rows ----------------
__global__ __launch_bounds__(256) void k_refine(const float* __restrict__ x,
                                                const float* __restrict__ mem,
                                                const double* __restrict__ inv64,
                                                const unsigned int* __restrict__ flagbits,
                                                float* __restrict__ out_near) {
  unsigned int mask = flagbits[blockIdx.x];
  if (mask == 0u) return;                   // uniform; nearly all blocks exit
  const int tid = threadIdx.x;
  const int lane = tid & 63;
  const int wid = tid >> 6;
  __shared__ double bval[4];
  __shared__ int bidx[4];
  while (mask) {
    int r = __ffs(mask) - 1;
    mask &= (mask - 1u);
    int rrow = blockIdx.x * 16 + r;
    const float* __restrict__ xr = x + (size_t)rrow * DIM;
    double xd[16];
#pragma unroll
    for (int i = 0; i < 16; ++i) xd[i] = (double)xr[lane + 64 * i];
    double best = -1e300;
    int bi = 0;
    for (int q = 0; q < 10; ++q) {
      int m = wid * 10 + q;
      const float* __restrict__ mr = mem + (size_t)m * DIM;
      double s = 0.0;
#pragma unroll
      for (int i = 0; i < 16; ++i) s = fma(xd[i], (double)mr[lane + 64 * i], s);
#pragma unroll
      for (int off = 32; off > 0; off >>= 1) s += __shfl_xor(s, off, 64);
      double v = s * inv64[m];              // identical (bitwise) across lanes
      if (v > best) { best = v; bi = m; }   // strict > keeps lowest m on ties
    }
    if (lane == 0) { bval[wid] = best; bidx[wid] = bi; }
    __syncthreads();
    double gv = bval[0];
    int gi = bidx[0];
#pragma unroll
    for (int gg = 1; gg < 4; ++gg) {
      if (bval[gg] > gv) { gv = bval[gg]; gi = bidx[gg]; }
    }
    const float4* __restrict__ src = (const float4*)mem + (size_t)gi * (DIM / 4);
    float4* __restrict__ dst = (float4*)out_near + (size_t)rrow * (DIM / 4);
    dst[tid] = src[tid];                    // 256 x 16B = full row, coalesced
    __syncthreads();                        // LDS reuse guard for next flagged row
  }
}

extern "C" void kernel_launch(void* const* d_in, const int* in_sizes, int n_in,
                              void* d_out, int out_size, void* d_ws, size_t ws_size,
                              hipStream_t stream) {
  const float* x   = (const float*)d_in[0];
  const float* mem = (const float*)d_in[1];
  // d_in[2] = top_k (unused: reference only consumes idx[:,0], i.e. the argmax)

  const int n_rows = in_sizes[0] / DIM;          // 65536
  float* out_near = (float*)d_out;
  float* out_x    = (float*)d_out + (size_t)n_rows * DIM;

  double* inv64 = (double*)d_ws;
  float*  inv32 = (float*)((char*)d_ws + 320);
  unsigned int* flagbits = (unsigned int*)((char*)d_ws + 512);
  unsigned short* BH = (unsigned short*)((char*)d_ws + 32768);
  unsigned short* BL = (unsigned short*)((char*)d_ws + 131072);

  hipLaunchKernelGGL(k_norms, dim3(NMEM), dim3(64), 0, stream, mem, inv64, inv32);
  hipLaunchKernelGGL(k_prep,  dim3(48),   dim3(256), 0, stream, mem, inv32, BH, BL);
  hipLaunchKernelGGL(k_main,  dim3(n_rows / 64), dim3(256), 0, stream,
                     x, mem, BH, BL, out_near, out_x, flagbits);
  hipLaunchKernelGGL(k_refine, dim3(n_rows / 16), dim3(256), 0, stream,
                     x, mem, inv64, flagbits, out_near);
}

// Round 19
// 188.562 us; speedup vs baseline: 1.5831x; 1.0496x over previous
//
#include <hip/hip_runtime.h>

// Problem: nearest = memory[argmax_m cosine(x_row, memory_m)], plus copy of x.
//   x: 65536 x 1024 f32, memory: 40 x 1024 f32, out = [nearest | x-copy]
//
// R19 = R18 (198us, all-HBM-instructions-1KB-contiguous) + staging loop
// restructured to LOAD-ALL-THEN-CONSUME: g[0..15] issued back-to-back (16
// loads in flight, ONE HBM latency exposure per quarter) before any
// nt-store/ds_write consumes them. R18's unroll-4 interleave kept only 4
// loads in flight -> ~4 serial latencies per quarter (the remaining gap).
//
// d_ws layout (bytes):
//   [0,      320) : double inv64[40]
//   [320,    480) : float  inv32[40]
//   [512,  16896) : uint flagbits[4096]  (16-bit mask per 16-row wave)
//   [32768,131072): ushort BH[32][48][32] (bf16 hi of mem*inv32, step-major)
//   [131072,229376): ushort BL[32][48][32] (bf16 lo, step-major)

#define DIM 1024
#define NMEM 40

typedef float  vf4 __attribute__((ext_vector_type(4)));
typedef float  f4a __attribute__((ext_vector_type(4)));
typedef short  s8v __attribute__((ext_vector_type(8)));

union FragU { s8v v; unsigned int u[4]; };

constexpr float TAU = 2.5e-4f;   // normalized top-2 gap below which f64 re-resolve

// ---------------- Kernel 1: memory-row inverse norms (f32 + f64) ----------------
__global__ __launch_bounds__(64) void k_norms(const float* __restrict__ mem,
                                              double* __restrict__ inv64,
                                              float* __restrict__ inv32) {
  const int m = blockIdx.x;      // 40 blocks, 1 wave each
  const int lane = threadIdx.x;
  const float* __restrict__ row = mem + (size_t)m * DIM;
  double s = 0.0;
#pragma unroll
  for (int i = 0; i < DIM / 64; ++i) {
    double v = (double)row[lane + 64 * i];
    s = fma(v, v, s);
  }
#pragma unroll
  for (int off = 32; off > 0; off >>= 1) s += __shfl_xor(s, off, 64);
  if (lane == 0) {
    double n = sqrt(s);
    n = (n > 1e-8) ? n : 1e-8;
    inv64[m] = 1.0 / n;
    inv32[m] = (float)(1.0 / n);
  }
}

// ------------- Kernel 1b: split normalized memory -> step-major bf16 hi/lo -------------
__global__ __launch_bounds__(256) void k_prep(const float* __restrict__ mem,
                                              const float* __restrict__ inv32,
                                              unsigned short* __restrict__ BH,
                                              unsigned short* __restrict__ BL) {
  const int m = blockIdx.x;            // 0..47 (40 real + 8 zero-pad)
  const int k0 = threadIdx.x * 4;      // 1024/256 = 4 elems/thread
#pragma unroll
  for (int j = 0; j < 4; ++j) {
    const int k = k0 + j;
    const size_t dst = (size_t)(k >> 5) * (48 * 32) + (size_t)m * 32 + (k & 31);
    if (m < NMEM) {
      const float s = inv32[m];
      float w = mem[(size_t)m * DIM + k] * s;
      unsigned int u = __builtin_bit_cast(unsigned int, w);
      BH[dst] = (unsigned short)(u >> 16);
      float hf = __builtin_bit_cast(float, u & 0xFFFF0000u);
      float lo = w - hf;
      BL[dst] = (unsigned short)(__builtin_bit_cast(unsigned int, lo) >> 16);
    } else {
      BH[dst] = 0;
      BL[dst] = 0;
    }
  }
}

// ---------------- Kernel 2: MFMA sims + argmax + gather + x-copy ----------------
// Block = 256 thr = 4 independent waves (no barriers). Wave = 16 x-rows.
// Per K-quarter q: LOAD all 16 rows (1KB contiguous each, 16 in flight),
// then CONSUME (1KB-contiguous nt x-copy + swizzled ds_write), then 8 steps
// of {B-loads (1KB contiguous L2), A-frags from LDS, split, 12 MFMA}.
// C layout (m89-verified): lane holds D[(l>>4)*4+j][(l&15)+16*tile].
__global__ __launch_bounds__(256, 2) void k_main(const float* __restrict__ x,
                                                 const float* __restrict__ mem,
                                                 const unsigned short* __restrict__ BH,
                                                 const unsigned short* __restrict__ BL,
                                                 float* __restrict__ out_near,
                                                 float* __restrict__ out_x,
                                                 unsigned int* __restrict__ flagbits) {
  __shared__ vf4 xq4[4 * 16 * 64];     // exactly 64 KB: wave w owns [w*1024, w*1024+1024)

  const int tid  = threadIdx.x;
  const int lane = tid & 63;
  const int w    = __builtin_amdgcn_readfirstlane(tid >> 6);
  const int row  = lane & 15;          // x-row within wave tile / m-col within tile
  const int kg   = lane >> 4;          // k-subslice group (0..3)
  const int rowbase = blockIdx.x * 64 + w * 16;

  const unsigned short* __restrict__ bp = BH + row * 32 + kg * 8;  // + T*1536 + tt*512
  const unsigned short* __restrict__ lp = BL + row * 32 + kg * 8;

  f4a acc[3];
#pragma unroll
  for (int t = 0; t < 3; ++t) acc[t] = (f4a){0.f, 0.f, 0.f, 0.f};
  float nx = 0.f;

  const int q0 = (blockIdx.x + w) & 3;   // quarter-phase rotation (R16 de-phasing)
  vf4* __restrict__ xw = xq4 + w * 1024;

#pragma unroll 1
  for (int qq = 0; qq < 4; ++qq) {
    const int q = (q0 + qq) & 3;
    // ---- stage quarter q: LOAD-ALL (16 x 1KB, back-to-back) ... ----
    vf4 g[16];
#pragma unroll
    for (int r = 0; r < 16; ++r)
      g[r] = *(const vf4*)(x + (size_t)(rowbase + r) * DIM + q * 256 + lane * 4);
    // ---- ... THEN-CONSUME (nt x-copy + swizzled ds_write, in retirement order) ----
#pragma unroll
    for (int r = 0; r < 16; ++r) {
      __builtin_nontemporal_store(g[r],
          (vf4*)(out_x + (size_t)(rowbase + r) * DIM + q * 256 + lane * 4));
      xw[r * 64 + (lane ^ (r & 7))] = g[r];   // XOR-swizzled (conflict-min)
    }
    // ---- compute 8 K-steps of this quarter ----
#pragma unroll
    for (int tl = 0; tl < 8; ++tl) {
      const int T = q * 8 + tl;
      s8v bh[3], bl[3];                 // B first (issue order; L2, 1KB contiguous)
#pragma unroll
      for (int tt = 0; tt < 3; ++tt) {
        bh[tt] = *(const s8v*)(bp + (size_t)T * 1536 + tt * 512);
        bl[tt] = *(const s8v*)(lp + (size_t)T * 1536 + tt * 512);
      }
      const int f = tl * 8 + kg * 2;
      vf4 a0 = xw[row * 64 + (f ^ (row & 7))];
      vf4 a1 = xw[row * 64 + ((f + 1) ^ (row & 7))];
      nx = fmaf(a0.x, a0.x, fmaf(a0.y, a0.y, fmaf(a0.z, a0.z, fmaf(a0.w, a0.w, nx))));
      nx = fmaf(a1.x, a1.x, fmaf(a1.y, a1.y, fmaf(a1.z, a1.z, fmaf(a1.w, a1.w, nx))));
      FragU ah, al;
      {
        float fbuf[8] = {a0.x, a0.y, a0.z, a0.w, a1.x, a1.y, a1.z, a1.w};
#pragma unroll
        for (int p = 0; p < 4; ++p) {
          unsigned int u0 = __builtin_bit_cast(unsigned int, fbuf[2 * p]);
          unsigned int u1 = __builtin_bit_cast(unsigned int, fbuf[2 * p + 1]);
          ah.u[p] = (u1 & 0xFFFF0000u) | (u0 >> 16);
          float h0 = __builtin_bit_cast(float, u0 & 0xFFFF0000u);
          float h1 = __builtin_bit_cast(float, u1 & 0xFFFF0000u);
          float l0 = fbuf[2 * p] - h0;
          float l1 = fbuf[2 * p + 1] - h1;
          al.u[p] = (__builtin_bit_cast(unsigned int, l1) & 0xFFFF0000u) |
                    (__builtin_bit_cast(unsigned int, l0) >> 16);
        }
      }
#pragma unroll
      for (int tt = 0; tt < 3; ++tt) {
        acc[tt] = __builtin_amdgcn_mfma_f32_16x16x32_bf16(ah.v, bh[tt], acc[tt], 0, 0, 0);
        acc[tt] = __builtin_amdgcn_mfma_f32_16x16x32_bf16(ah.v, bl[tt], acc[tt], 0, 0, 0);
        acc[tt] = __builtin_amdgcn_mfma_f32_16x16x32_bf16(al.v, bh[tt], acc[tt], 0, 0, 0);
        acc[tt] = __builtin_amdgcn_mfma_f32_16x16x32_bf16(al.v, bl[tt], acc[tt], 0, 0, 0);
      }
    }
  }

  // ||x||^2: sum the 4 k-groups (lanes l, l^16, l^32, l^48 share row l&15)
  nx += __shfl_xor(nx, 16, 64);
  nx += __shfl_xor(nx, 32, 64);
  // now every lane: nx = ||x_{row=lane&15}||^2

  // per-lane top-2: lane holds sims for rows (l>>4)*4+j, m-cols (l&15)+16t
  float v1[4], v2[4];
  int   i1[4];
#pragma unroll
  for (int j = 0; j < 4; ++j) {
    float c0 = acc[0][j], c1 = acc[1][j];
    float c2 = (row < 8) ? acc[2][j] : -3.4e38f;   // cols 40-47 are pad
    float a1 = c0, a2 = -3.4e38f;
    int   ai = row;
    if (c1 > a1) { a2 = a1; a1 = c1; ai = row + 16; } else a2 = c1;
    if (c2 > a1) { a2 = a1; a1 = c2; ai = row + 32; } else if (c2 > a2) a2 = c2;
    v1[j] = a1; v2[j] = a2; i1[j] = ai;
  }
#pragma unroll
  for (int st = 1; st < 16; st <<= 1) {  // butterfly: 16 lanes of each group converge
#pragma unroll
    for (int j = 0; j < 4; ++j) {
      float o1 = __shfl_xor(v1[j], st, 64);
      float o2 = __shfl_xor(v2[j], st, 64);
      int   oi = __shfl_xor(i1[j], st, 64);
      if (o1 > v1[j]) { v2[j] = fmaxf(v1[j], o2); v1[j] = o1; i1[j] = oi; }
      else            { v2[j] = fmaxf(v2[j], o1); }           // tie -> gap 0 -> flagged
    }
  }
  // flags: group g (= lane>>4) holds rows 4g+j; nx fetched from row-owner lane
  const int g = lane >> 4;
  float nx0 = __shfl(nx, 4 * g + 0, 64);
  float nx1 = __shfl(nx, 4 * g + 1, 64);
  float nx2 = __shfl(nx, 4 * g + 2, 64);
  float nx3 = __shfl(nx, 4 * g + 3, 64);
  int fl0 = !((v1[0] - v2[0]) * rsqrtf(fmaxf(nx0, 1e-30f)) >= TAU);  // NaN-safe
  int fl1 = !((v1[1] - v2[1]) * rsqrtf(fmaxf(nx1, 1e-30f)) >= TAU);
  int fl2 = !((v1[2] - v2[2]) * rsqrtf(fmaxf(nx2, 1e-30f)) >= TAU);
  int fl3 = !((v1[3] - v2[3]) * rsqrtf(fmaxf(nx3, 1e-30f)) >= TAU);
  // redistribute (R18 pattern): shfl each flag register individually from the
  // row-owner group's lane 0, then select with the READING lane's j.
  const int srcl = 16 * ((lane & 15) >> 2);
  int f0 = __shfl(fl0, srcl, 64);
  int f1 = __shfl(fl1, srcl, 64);
  int f2 = __shfl(fl2, srcl, 64);
  int f3 = __shfl(fl3, srcl, 64);
  const int jsel = lane & 3;
  int flv = (jsel & 2) ? ((jsel & 1) ? f3 : f2) : ((jsel & 1) ? f1 : f0);
  unsigned long long bmask = __ballot(flv != 0);
  if (lane == 0) flagbits[blockIdx.x * 4 + w] = (unsigned int)(bmask & 0xFFFFull);

  // gather-copy memory[amax] -> out_near (16 rows/wave, coalesced nt full lines)
  // (i1[r&3] is compile-time-indexed on BOTH sides of the shfl -> correct)
  const vf4* __restrict__ m4 = (const vf4*)mem;
#pragma unroll
  for (int r = 0; r < 16; ++r) {
    int am = __shfl(i1[r & 3], 16 * (r >> 2), 64);
    am = __builtin_amdgcn_readfirstlane(am);
    const vf4* __restrict__ src = m4 + (size_t)am * (DIM / 4);
    vf4* __restrict__ dst = (vf4*)out_near + (size_t)(rowbase + r) * (DIM / 4);
#pragma unroll
    for (int j = 0; j < 4; ++j) {
      vf4 v = src[lane + 64 * j];
      __builtin_nontemporal_store(v, &dst[lane + 64 * j]);
    }
  }
}

// ---------------- Kernel 3: f64 re-resolution of razor-thin rows ----------------
__global__ __launch_bounds__(256) void k_refine(const float* __restrict__ x,
                                                const float* __restrict__ mem,
                                                const double* __restrict__ inv64,
                                                const unsigned int* __restrict__ flagbits,
                                                float* __restrict__ out_near) {
  unsigned int mask = flagbits[blockIdx.x];
  if (mask == 0u) return;                   // uniform; nearly all blocks exit
  const int tid = threadIdx.x;
  const int lane = tid & 63;
  const int wid = tid >> 6;
  __shared__ double bval[4];
  __shared__ int bidx[4];
  while (mask) {
    int r = __ffs(mask) - 1;
    mask &= (mask - 1u);
    int rrow = blockIdx.x * 16 + r;
    const float* __restrict__ xr = x + (size_t)rrow * DIM;
    double xd[16];
#pragma unroll
    for (int i = 0; i < 16; ++i) xd[i] = (double)xr[lane + 64 * i];
    double best = -1e300;
    int bi = 0;
    for (int q = 0; q < 10; ++q) {
      int m = wid * 10 + q;
      const float* __restrict__ mr = mem + (size_t)m * DIM;
      double s = 0.0;
#pragma unroll
      for (int i = 0; i < 16; ++i) s = fma(xd[i], (double)mr[lane + 64 * i], s);
#pragma unroll
      for (int off = 32; off > 0; off >>= 1) s += __shfl_xor(s, off, 64);
      double v = s * inv64[m];              // identical (bitwise) across lanes
      if (v > best) { best = v; bi = m; }   // strict > keeps lowest m on ties
    }
    if (lane == 0) { bval[wid] = best; bidx[wid] = bi; }
    __syncthreads();
    double gv = bval[0];
    int gi = bidx[0];
#pragma unroll
    for (int gg = 1; gg < 4; ++gg) {
      if (bval[gg] > gv) { gv = bval[gg]; gi = bidx[gg]; }
    }
    const float4* __restrict__ src = (const float4*)mem + (size_t)gi * (DIM / 4);
    float4* __restrict__ dst = (float4*)out_near + (size_t)rrow * (DIM / 4);
    dst[tid] = src[tid];                    // 256 x 16B = full row, coalesced
    __syncthreads();                        // LDS reuse guard for next flagged row
  }
}

extern "C" void kernel_launch(void* const* d_in, const int* in_sizes, int n_in,
                              void* d_out, int out_size, void* d_ws, size_t ws_size,
                              hipStream_t stream) {
  const float* x   = (const float*)d_in[0];
  const float* mem = (const float*)d_in[1];
  // d_in[2] = top_k (unused: reference only consumes idx[:,0], i.e. the argmax)

  const int n_rows = in_sizes[0] / DIM;          // 65536
  float* out_near = (float*)d_out;
  float* out_x    = (float*)d_out + (size_t)n_rows * DIM;

  double* inv64 = (double*)d_ws;
  float*  inv32 = (float*)((char*)d_ws + 320);
  unsigned int* flagbits = (unsigned int*)((char*)d_ws + 512);
  unsigned short* BH = (unsigned short*)((char*)d_ws + 32768);
  unsigned short* BL = (unsigned short*)((char*)d_ws + 131072);

  hipLaunchKernelGGL(k_norms, dim3(NMEM), dim3(64), 0, stream, mem, inv64, inv32);
  hipLaunchKernelGGL(k_prep,  dim3(48),   dim3(256), 0, stream, mem, inv32, BH, BL);
  hipLaunchKernelGGL(k_main,  dim3(n_rows / 64), dim3(256), 0, stream,
                     x, mem, BH, BL, out_near, out_x, flagbits);
  hipLaunchKernelGGL(k_refine, dim3(n_rows / 16), dim3(256), 0, stream,
                     x, mem, inv64, flagbits, out_near);
}